// Round 1
// baseline (38.107 us; speedup 1.0000x reference)
//
#include <hip/hip_runtime.h>

#define NT 256

// DB4 decomposition filters (pywt convention)
__device__ __constant__ float LO[8] = {
    -0.010597401784997278f,  0.032883011666982945f,  0.030841381835986965f,
    -0.18703481171888114f,  -0.02798376941698385f,   0.6308807679295904f,
     0.7148465705525415f,    0.23037781330885523f};
// HI[k] = LO[7-k] * (k even ? -1 : +1)
__device__ __constant__ float HI[8] = {
    -0.23037781330885523f,   0.7148465705525415f,   -0.6308807679295904f,
    -0.02798376941698385f,   0.18703481171888114f,   0.030841381835986965f,
    -0.032883011666982945f, -0.010597401784997278f};

// Level sizes: 4096 -> 2051 -> 1029 -> 518 -> 262
// Output layout (flat, concatenated in return order):
//   cA4 [4096,262] | cD4 [4096,262] | cD3 [4096,518] | cD2 [4096,1029] | cD1 [4096,2051]
constexpr int B_ROWS = 4096;
constexpr int L1 = 4096, N1 = 2051, N2 = 1029, N3 = 518, N4 = 262;
constexpr size_t OFF_CA4 = 0;
constexpr size_t OFF_CD4 = (size_t)B_ROWS * N4;                 // 1,073,152
constexpr size_t OFF_CD3 = OFF_CD4 + (size_t)B_ROWS * N4;       // 2,146,304
constexpr size_t OFF_CD2 = OFF_CD3 + (size_t)B_ROWS * N3;       // 4,268,032
constexpr size_t OFF_CD1 = OFF_CD2 + (size_t)B_ROWS * N2;       // 8,482,816

// One DWT level: src[0..L-1] in LDS -> cA into dstA (LDS), cD scaled to global.
__device__ __forceinline__ void dwt_level(const float* __restrict__ src, int L,
                                          float* __restrict__ dstA,
                                          float* __restrict__ outD,
                                          float wd, float bd) {
    const int N = (L + 7) >> 1;
    for (int t = threadIdx.x; t < N; t += NT) {
        const int base = 2 * t + 1;
        float slo = 0.f, shi = 0.f;
#pragma unroll
        for (int j = 0; j < 8; ++j) {
            int q = base - j;
            q = (q < 0) ? (-1 - q) : q;           // left symmetric reflect
            q = (q >= L) ? (2 * L - 1 - q) : q;   // right symmetric reflect
            const float v = src[q];
            slo = fmaf(LO[j], v, slo);
            shi = fmaf(HI[j], v, shi);
        }
        dstA[t] = slo;
        outD[t] = fmaf(wd, shi, bd);
    }
}

// Final level: both cA and cD go (scaled) to global.
__device__ __forceinline__ void dwt_level_last(const float* __restrict__ src, int L,
                                               float* __restrict__ outA, float wa, float ba,
                                               float* __restrict__ outD, float wd, float bd) {
    const int N = (L + 7) >> 1;
    for (int t = threadIdx.x; t < N; t += NT) {
        const int base = 2 * t + 1;
        float slo = 0.f, shi = 0.f;
#pragma unroll
        for (int j = 0; j < 8; ++j) {
            int q = base - j;
            q = (q < 0) ? (-1 - q) : q;
            q = (q >= L) ? (2 * L - 1 - q) : q;
            const float v = src[q];
            slo = fmaf(LO[j], v, slo);
            shi = fmaf(HI[j], v, shi);
        }
        outA[t] = fmaf(wa, slo, ba);
        outD[t] = fmaf(wd, shi, bd);
    }
}

__global__ __launch_bounds__(NT) void lwt_kernel(const float* __restrict__ x,
                                                 const float* __restrict__ w,
                                                 const float* __restrict__ bias,
                                                 float* __restrict__ out) {
    __shared__ float sA[L1];      // 16 KB
    __shared__ float sB[N1];      // 8.2 KB
    const int row = blockIdx.x;
    const int tid = threadIdx.x;

    // Stage the row into LDS, 16B per lane.
    {
        const float4* src = reinterpret_cast<const float4*>(x + (size_t)row * L1);
        float4* dst = reinterpret_cast<float4*>(sA);
#pragma unroll
        for (int i = 0; i < L1 / 4 / NT; ++i)
            dst[tid + i * NT] = src[tid + i * NT];
    }

    // Per-coefficient affine params (uniform loads, L2-resident).
    const float w0 = w[0], w1 = w[1], w2 = w[2], w3 = w[3], w4 = w[4];
    const float b0 = bias[0], b1 = bias[1], b2 = bias[2], b3 = bias[3], b4 = bias[4];

    float* outCD1 = out + OFF_CD1 + (size_t)row * N1;
    float* outCD2 = out + OFF_CD2 + (size_t)row * N2;
    float* outCD3 = out + OFF_CD3 + (size_t)row * N3;
    float* outCD4 = out + OFF_CD4 + (size_t)row * N4;
    float* outCA4 = out + OFF_CA4 + (size_t)row * N4;

    __syncthreads();
    dwt_level(sA, L1, sB, outCD1, w4, b4);   // 4096 -> 2051
    __syncthreads();
    dwt_level(sB, N1, sA, outCD2, w3, b3);   // 2051 -> 1029
    __syncthreads();
    dwt_level(sA, N2, sB, outCD3, w2, b2);   // 1029 -> 518
    __syncthreads();
    dwt_level_last(sB, N3, outCA4, w0, b0, outCD4, w1, b1);  // 518 -> 262
}

extern "C" void kernel_launch(void* const* d_in, const int* in_sizes, int n_in,
                              void* d_out, int out_size, void* d_ws, size_t ws_size,
                              hipStream_t stream) {
    const float* x = (const float*)d_in[0];
    const float* w = (const float*)d_in[1];
    const float* b = (const float*)d_in[2];
    float* out = (float*)d_out;
    lwt_kernel<<<dim3(B_ROWS), dim3(NT), 0, stream>>>(x, w, b, out);
}

// Round 2
// 28.879 us; speedup vs baseline: 1.3196x; 1.3196x over previous
//
#include <hip/hip_runtime.h>

#define NT 256

// DB4 decomposition low-pass filter (pywt convention)
// l0..l7
#define L0 -0.010597401784997278f
#define L1f 0.032883011666982945f
#define L2f 0.030841381835986965f
#define L3f -0.18703481171888114f
#define L4f -0.02798376941698385f
#define L5f 0.6308807679295904f
#define L6f 0.7148465705525415f
#define L7f 0.23037781330885523f

// y_lo[t] = sum_j LO[j] * X(2t+1-j)  ==  sum_m LOR[m] * X(2t-6+m), LOR[m]=LO[7-m]
// y_hi[t] = sum_m HIR[m] * X(2t-6+m), HIR[m]=LO[m]*(m odd ? -1 : +1)

constexpr int B_ROWS = 4096;
constexpr int LVL1 = 4096, N1 = 2051, N2 = 1029, N3 = 518, N4 = 262;
constexpr size_t OFF_CA4 = 0;
constexpr size_t OFF_CD4 = (size_t)B_ROWS * N4;
constexpr size_t OFF_CD3 = OFF_CD4 + (size_t)B_ROWS * N4;
constexpr size_t OFF_CD2 = OFF_CD3 + (size_t)B_ROWS * N3;
constexpr size_t OFF_CD1 = OFF_CD2 + (size_t)B_ROWS * N2;

// Clamped (symmetric-reflect) single-output pair for boundary t.
__device__ __forceinline__ void dwt_one_clamped(const float* __restrict__ src, int L, int t,
                                                float& slo, float& shi) {
    constexpr float LOR[8] = {L7f, L6f, L5f, L4f, L3f, L2f, L1f, L0};
    constexpr float HIR[8] = {L0, -L1f, L2f, -L3f, L4f, -L5f, L6f, -L7f};
    const int idx0 = 2 * t - 6;
    slo = 0.f; shi = 0.f;
#pragma unroll
    for (int m = 0; m < 8; ++m) {
        int q = idx0 + m;
        q = (q < 0) ? (-1 - q) : q;
        q = (q >= L) ? (2 * L - 1 - q) : q;
        const float v = src[q];
        slo = fmaf(LOR[m], v, slo);
        shi = fmaf(HIR[m], v, shi);
    }
}

// One DWT level. cA -> dstA (raw if !SCALE_A, else affine with wa/ba),
// cD -> outD with affine wd/bd.
template <bool SCALE_A>
__device__ __forceinline__ void dwt_level(const float* __restrict__ src, int L,
                                          float* __restrict__ dstA, float wa, float ba,
                                          float* __restrict__ outD, float wd, float bd) {
    constexpr float LOR[8] = {L7f, L6f, L5f, L4f, L3f, L2f, L1f, L0};
    constexpr float HIR[8] = {L0, -L1f, L2f, -L3f, L4f, -L5f, L6f, -L7f};
    const int N = (L + 7) >> 1;
    const int tmax = (L - 2) >> 1;   // last clamp-free output index
    const int tid = threadIdx.x;

    // Interior: taps 2t-6 .. 2t+1 all in [0, L). 8B-aligned window.
    for (int t = 3 + tid; t <= tmax; t += NT) {
        const float2* p = reinterpret_cast<const float2*>(src + 2 * t - 6);
        const float2 a = p[0], b = p[1], c = p[2], d = p[3];
        float w0 = a.x, w1 = a.y, w2 = b.x, w3 = b.y, w4 = c.x, w5 = c.y, w6 = d.x, w7 = d.y;
        float slo, shi;
        slo = LOR[0] * w0;            shi = HIR[0] * w0;
        slo = fmaf(LOR[1], w1, slo);  shi = fmaf(HIR[1], w1, shi);
        slo = fmaf(LOR[2], w2, slo);  shi = fmaf(HIR[2], w2, shi);
        slo = fmaf(LOR[3], w3, slo);  shi = fmaf(HIR[3], w3, shi);
        slo = fmaf(LOR[4], w4, slo);  shi = fmaf(HIR[4], w4, shi);
        slo = fmaf(LOR[5], w5, slo);  shi = fmaf(HIR[5], w5, shi);
        slo = fmaf(LOR[6], w6, slo);  shi = fmaf(HIR[6], w6, shi);
        slo = fmaf(LOR[7], w7, slo);  shi = fmaf(HIR[7], w7, shi);
        dstA[t] = SCALE_A ? fmaf(wa, slo, ba) : slo;
        outD[t] = fmaf(wd, shi, bd);
    }

    // Left boundary: t = 0,1,2
    if (tid < 3) {
        float slo, shi;
        dwt_one_clamped(src, L, tid, slo, shi);
        dstA[tid] = SCALE_A ? fmaf(wa, slo, ba) : slo;
        outD[tid] = fmaf(wd, shi, bd);
    }
    // Right boundary: t = tmax+1 .. N-1 (at most 4)
    {
        const int t = tmax + 1 + tid;
        if (tid < 4 && t < N) {
            float slo, shi;
            dwt_one_clamped(src, L, t, slo, shi);
            dstA[t] = SCALE_A ? fmaf(wa, slo, ba) : slo;
            outD[t] = fmaf(wd, shi, bd);
        }
    }
}

__global__ __launch_bounds__(NT) void lwt_kernel(const float* __restrict__ x,
                                                 const float* __restrict__ w,
                                                 const float* __restrict__ bias,
                                                 float* __restrict__ out) {
    __shared__ __align__(16) float sA[LVL1];   // 16 KB
    __shared__ __align__(16) float sB[N1];     // 8.2 KB
    const int row = blockIdx.x;
    const int tid = threadIdx.x;

    // Stage the row into LDS, 16B per lane.
    {
        const float4* src = reinterpret_cast<const float4*>(x + (size_t)row * LVL1);
        float4* dst = reinterpret_cast<float4*>(sA);
#pragma unroll
        for (int i = 0; i < LVL1 / 4 / NT; ++i)
            dst[tid + i * NT] = src[tid + i * NT];
    }

    const float w0 = w[0], w1 = w[1], w2 = w[2], w3 = w[3], w4 = w[4];
    const float b0 = bias[0], b1 = bias[1], b2 = bias[2], b3 = bias[3], b4 = bias[4];

    float* outCD1 = out + OFF_CD1 + (size_t)row * N1;
    float* outCD2 = out + OFF_CD2 + (size_t)row * N2;
    float* outCD3 = out + OFF_CD3 + (size_t)row * N3;
    float* outCD4 = out + OFF_CD4 + (size_t)row * N4;
    float* outCA4 = out + OFF_CA4 + (size_t)row * N4;

    __syncthreads();
    dwt_level<false>(sA, LVL1, sB, 0.f, 0.f, outCD1, w4, b4);   // 4096 -> 2051
    __syncthreads();
    dwt_level<false>(sB, N1, sA, 0.f, 0.f, outCD2, w3, b3);     // 2051 -> 1029
    __syncthreads();
    dwt_level<false>(sA, N2, sB, 0.f, 0.f, outCD3, w2, b2);     // 1029 -> 518
    __syncthreads();
    dwt_level<true>(sB, N3, outCA4, w0, b0, outCD4, w1, b1);    // 518 -> 262
}

extern "C" void kernel_launch(void* const* d_in, const int* in_sizes, int n_in,
                              void* d_out, int out_size, void* d_ws, size_t ws_size,
                              hipStream_t stream) {
    const float* x = (const float*)d_in[0];
    const float* wp = (const float*)d_in[1];
    const float* bp = (const float*)d_in[2];
    float* out = (float*)d_out;
    lwt_kernel<<<dim3(B_ROWS), dim3(NT), 0, stream>>>(x, wp, bp, out);
}

// Round 3
// 28.239 us; speedup vs baseline: 1.3494x; 1.0226x over previous
//
#include <hip/hip_runtime.h>

#define NT 256

// DB4 decomposition low-pass filter (pywt convention), l0..l7
#define L0 -0.010597401784997278f
#define L1f 0.032883011666982945f
#define L2f 0.030841381835986965f
#define L3f -0.18703481171888114f
#define L4f -0.02798376941698385f
#define L5f 0.6308807679295904f
#define L6f 0.7148465705525415f
#define L7f 0.23037781330885523f

// y_lo[t] = sum_m LOR[m] * X(2t-6+m), LOR[m]=LO[7-m]
// y_hi[t] = sum_m HIR[m] * X(2t-6+m), HIR[m]=LO[m]*(m odd ? -1 : +1)

constexpr int B_ROWS = 4096;
constexpr int LVL1 = 4096, N1 = 2051, N2 = 1029, N3 = 518, N4 = 262;
constexpr size_t OFF_CA4 = 0;
constexpr size_t OFF_CD4 = (size_t)B_ROWS * N4;
constexpr size_t OFF_CD3 = OFF_CD4 + (size_t)B_ROWS * N4;
constexpr size_t OFF_CD2 = OFF_CD3 + (size_t)B_ROWS * N3;
constexpr size_t OFF_CD1 = OFF_CD2 + (size_t)B_ROWS * N2;

// Clamped (symmetric-reflect) single-output pair for boundary t. src may be global or LDS.
__device__ __forceinline__ void dwt_one_clamped(const float* __restrict__ src, int L, int t,
                                                float& slo, float& shi) {
    constexpr float LOR[8] = {L7f, L6f, L5f, L4f, L3f, L2f, L1f, L0};
    constexpr float HIR[8] = {L0, -L1f, L2f, -L3f, L4f, -L5f, L6f, -L7f};
    const int idx0 = 2 * t - 6;
    slo = 0.f; shi = 0.f;
#pragma unroll
    for (int m = 0; m < 8; ++m) {
        int q = idx0 + m;
        q = (q < 0) ? (-1 - q) : q;
        q = (q >= L) ? (2 * L - 1 - q) : q;
        const float v = src[q];
        slo = fmaf(LOR[m], v, slo);
        shi = fmaf(HIR[m], v, shi);
    }
}

// One DWT level from LDS (levels 2..4). cA -> dstA, cD -> outD (affine).
template <bool SCALE_A>
__device__ __forceinline__ void dwt_level(const float* __restrict__ src, int L,
                                          float* __restrict__ dstA, float wa, float ba,
                                          float* __restrict__ outD, float wd, float bd) {
    constexpr float LOR[8] = {L7f, L6f, L5f, L4f, L3f, L2f, L1f, L0};
    constexpr float HIR[8] = {L0, -L1f, L2f, -L3f, L4f, -L5f, L6f, -L7f};
    const int N = (L + 7) >> 1;
    const int tmax = (L - 2) >> 1;
    const int tid = threadIdx.x;

    for (int t = 3 + tid; t <= tmax; t += NT) {
        const float2* p = reinterpret_cast<const float2*>(src + 2 * t - 6);
        const float2 a = p[0], b = p[1], c = p[2], d = p[3];
        float slo, shi;
        slo = LOR[0] * a.x;            shi = HIR[0] * a.x;
        slo = fmaf(LOR[1], a.y, slo);  shi = fmaf(HIR[1], a.y, shi);
        slo = fmaf(LOR[2], b.x, slo);  shi = fmaf(HIR[2], b.x, shi);
        slo = fmaf(LOR[3], b.y, slo);  shi = fmaf(HIR[3], b.y, shi);
        slo = fmaf(LOR[4], c.x, slo);  shi = fmaf(HIR[4], c.x, shi);
        slo = fmaf(LOR[5], c.y, slo);  shi = fmaf(HIR[5], c.y, shi);
        slo = fmaf(LOR[6], d.x, slo);  shi = fmaf(HIR[6], d.x, shi);
        slo = fmaf(LOR[7], d.y, slo);  shi = fmaf(HIR[7], d.y, shi);
        dstA[t] = SCALE_A ? fmaf(wa, slo, ba) : slo;
        outD[t] = fmaf(wd, shi, bd);
    }
    if (tid < 3) {
        float slo, shi;
        dwt_one_clamped(src, L, tid, slo, shi);
        dstA[tid] = SCALE_A ? fmaf(wa, slo, ba) : slo;
        outD[tid] = fmaf(wd, shi, bd);
    }
    {
        const int t = tmax + 1 + tid;
        if (tid < 4 && t < N) {
            float slo, shi;
            dwt_one_clamped(src, L, t, slo, shi);
            dstA[t] = SCALE_A ? fmaf(wa, slo, ba) : slo;
            outD[t] = fmaf(wd, shi, bd);
        }
    }
}

__global__ __launch_bounds__(NT) void lwt_kernel(const float* __restrict__ x,
                                                 const float* __restrict__ w,
                                                 const float* __restrict__ bias,
                                                 float* __restrict__ out) {
    __shared__ __align__(16) float P[N1];  // cA1, later reused for cA3
    __shared__ __align__(16) float Q[N2];  // cA2
    const int row = blockIdx.x;
    const int tid = threadIdx.x;
    const float* __restrict__ xr = x + (size_t)row * LVL1;

    const float w0 = w[0], w1 = w[1], w2 = w[2], w3 = w[3], w4 = w[4];
    const float b0 = bias[0], b1 = bias[1], b2 = bias[2], b3 = bias[3], b4 = bias[4];

    float* outCD1 = out + OFF_CD1 + (size_t)row * N1;
    float* outCD2 = out + OFF_CD2 + (size_t)row * N2;
    float* outCD3 = out + OFF_CD3 + (size_t)row * N3;
    float* outCD4 = out + OFF_CD4 + (size_t)row * N4;
    float* outCA4 = out + OFF_CA4 + (size_t)row * N4;

    // ---- Level 1: directly from GLOBAL, 4 outputs per thread-iteration. ----
    // Interior t in [3, 2047]; 4-blocks t0 = 3+4k, k = 0..510 cover t = 3..2046.
    // Window floats: e = 8k .. 8k+15 (32B-aligned) -> 4x global_load_dwordx4.
    {
        constexpr float LOR[8] = {L7f, L6f, L5f, L4f, L3f, L2f, L1f, L0};
        constexpr float HIR[8] = {L0, -L1f, L2f, -L3f, L4f, -L5f, L6f, -L7f};
        for (int k = tid; k <= 510; k += NT) {
            const float4* p = reinterpret_cast<const float4*>(xr + 8 * k);
            const float4 v0 = p[0], v1 = p[1], v2 = p[2], v3 = p[3];
            float W[16] = {v0.x, v0.y, v0.z, v0.w, v1.x, v1.y, v1.z, v1.w,
                           v2.x, v2.y, v2.z, v2.w, v3.x, v3.y, v3.z, v3.w};
            const int t0 = 3 + 4 * k;
#pragma unroll
            for (int o = 0; o < 4; ++o) {
                float slo = LOR[0] * W[2 * o];
                float shi = HIR[0] * W[2 * o];
#pragma unroll
                for (int m = 1; m < 8; ++m) {
                    slo = fmaf(LOR[m], W[2 * o + m], slo);
                    shi = fmaf(HIR[m], W[2 * o + m], shi);
                }
                P[t0 + o] = slo;
                outCD1[t0 + o] = fmaf(w4, shi, b4);
            }
        }
        // Boundary + leftover: t in {0,1,2, 2047, 2048, 2049, 2050}
        if (tid < 7) {
            const int t = (tid < 3) ? tid : (2044 + tid);
            float slo, shi;
            dwt_one_clamped(xr, LVL1, t, slo, shi);
            P[t] = slo;
            outCD1[t] = fmaf(w4, shi, b4);
        }
    }

    __syncthreads();
    dwt_level<false>(P, N1, Q, 0.f, 0.f, outCD2, w3, b3);     // 2051 -> 1029 (cA2 in Q)
    __syncthreads();
    dwt_level<false>(Q, N2, P, 0.f, 0.f, outCD3, w2, b2);     // 1029 -> 518 (cA3 in P)
    __syncthreads();
    dwt_level<true>(P, N3, outCA4, w0, b0, outCD4, w1, b1);   // 518 -> 262
}

extern "C" void kernel_launch(void* const* d_in, const int* in_sizes, int n_in,
                              void* d_out, int out_size, void* d_ws, size_t ws_size,
                              hipStream_t stream) {
    const float* x = (const float*)d_in[0];
    const float* wp = (const float*)d_in[1];
    const float* bp = (const float*)d_in[2];
    float* out = (float*)d_out;
    lwt_kernel<<<dim3(B_ROWS), dim3(NT), 0, stream>>>(x, wp, bp, out);
}

// Round 4
// 27.691 us; speedup vs baseline: 1.3761x; 1.0198x over previous
//
#include <hip/hip_runtime.h>

#define NT 256

// DB4 decomposition low-pass filter (pywt convention), l0..l7
#define L0 -0.010597401784997278f
#define L1f 0.032883011666982945f
#define L2f 0.030841381835986965f
#define L3f -0.18703481171888114f
#define L4f -0.02798376941698385f
#define L5f 0.6308807679295904f
#define L6f 0.7148465705525415f
#define L7f 0.23037781330885523f

// y_lo[t] = sum_m LOR[m] * X(2t-6+m), LOR[m]=LO[7-m]
// y_hi[t] = sum_m HIR[m] * X(2t-6+m), HIR[m]=LO[m]*(m odd ? -1 : +1)

constexpr int B_ROWS = 4096;
constexpr int LVL1 = 4096, N1 = 2051, N2 = 1029, N3 = 518, N4 = 262;
constexpr size_t OFF_CA4 = 0;
constexpr size_t OFF_CD4 = (size_t)B_ROWS * N4;
constexpr size_t OFF_CD3 = OFF_CD4 + (size_t)B_ROWS * N4;
constexpr size_t OFF_CD2 = OFF_CD3 + (size_t)B_ROWS * N3;
constexpr size_t OFF_CD1 = OFF_CD2 + (size_t)B_ROWS * N2;

// Clamped (symmetric-reflect) single-output pair; clamps are no-ops for interior t.
__device__ __forceinline__ void dwt_one_clamped(const float* __restrict__ src, int L, int t,
                                                float& slo, float& shi) {
    constexpr float LOR[8] = {L7f, L6f, L5f, L4f, L3f, L2f, L1f, L0};
    constexpr float HIR[8] = {L0, -L1f, L2f, -L3f, L4f, -L5f, L6f, -L7f};
    const int idx0 = 2 * t - 6;
    slo = 0.f; shi = 0.f;
#pragma unroll
    for (int m = 0; m < 8; ++m) {
        int q = idx0 + m;
        q = (q < 0) ? (-1 - q) : q;
        q = (q >= L) ? (2 * L - 1 - q) : q;
        const float v = src[q];
        slo = fmaf(LOR[m], v, slo);
        shi = fmaf(HIR[m], v, shi);
    }
}

// One DWT level from LDS, 4 outputs per thread (t0 = 4m), float4 LDS I/O.
// cA -> dstA (LDS b128 raw if !SCALE_A, else affine scalar stores to global),
// cD -> outD scalar stores with affine folded into coefficients.
template <bool SCALE_A>
__device__ __forceinline__ void dwt_level_blk(const float* __restrict__ src, int L,
                                              float* __restrict__ dstA, float wa, float ba,
                                              float* __restrict__ outD, float wd, float bd) {
    constexpr float LOR[8] = {L7f, L6f, L5f, L4f, L3f, L2f, L1f, L0};
    constexpr float HIR[8] = {L0, -L1f, L2f, -L3f, L4f, -L5f, L6f, -L7f};
    const int N = (L + 7) >> 1;
    const int Mmax = (L - 8) >> 3;     // loads [8m-8, 8m+8) stay inside [0, L)
    const int tid = threadIdx.x;

    // Fold weight into the hi-pass filter; acc starts at bias.
    const float h0 = wd * HIR[0], h1 = wd * HIR[1], h2 = wd * HIR[2], h3 = wd * HIR[3],
                h4 = wd * HIR[4], h5 = wd * HIR[5], h6 = wd * HIR[6], h7 = wd * HIR[7];
    const float g0 = wa * LOR[0], g1 = wa * LOR[1], g2 = wa * LOR[2], g3 = wa * LOR[3],
                g4 = wa * LOR[4], g5 = wa * LOR[5], g6 = wa * LOR[6], g7 = wa * LOR[7];

    for (int m = 1 + tid; m <= Mmax; m += NT) {
        const float4* p = reinterpret_cast<const float4*>(src) + (2 * m - 2);
        const float4 v0 = p[0], v1 = p[1], v2 = p[2], v3 = p[3];
        const float W[16] = {v0.x, v0.y, v0.z, v0.w, v1.x, v1.y, v1.z, v1.w,
                             v2.x, v2.y, v2.z, v2.w, v3.x, v3.y, v3.z, v3.w};
        float accA[4], accD[4];
#pragma unroll
        for (int o = 0; o < 4; ++o) {
            // taps for output t0+o are W[2o+2 .. 2o+9]
            float sd = bd;
            sd = fmaf(h0, W[2 * o + 2], sd);
            sd = fmaf(h1, W[2 * o + 3], sd);
            sd = fmaf(h2, W[2 * o + 4], sd);
            sd = fmaf(h3, W[2 * o + 5], sd);
            sd = fmaf(h4, W[2 * o + 6], sd);
            sd = fmaf(h5, W[2 * o + 7], sd);
            sd = fmaf(h6, W[2 * o + 8], sd);
            sd = fmaf(h7, W[2 * o + 9], sd);
            accD[o] = sd;
            float sa;
            if (SCALE_A) {
                sa = ba;
                sa = fmaf(g0, W[2 * o + 2], sa);
                sa = fmaf(g1, W[2 * o + 3], sa);
                sa = fmaf(g2, W[2 * o + 4], sa);
                sa = fmaf(g3, W[2 * o + 5], sa);
                sa = fmaf(g4, W[2 * o + 6], sa);
                sa = fmaf(g5, W[2 * o + 7], sa);
                sa = fmaf(g6, W[2 * o + 8], sa);
                sa = fmaf(g7, W[2 * o + 9], sa);
            } else {
                sa = LOR[0] * W[2 * o + 2];
                sa = fmaf(LOR[1], W[2 * o + 3], sa);
                sa = fmaf(LOR[2], W[2 * o + 4], sa);
                sa = fmaf(LOR[3], W[2 * o + 5], sa);
                sa = fmaf(LOR[4], W[2 * o + 6], sa);
                sa = fmaf(LOR[5], W[2 * o + 7], sa);
                sa = fmaf(LOR[6], W[2 * o + 8], sa);
                sa = fmaf(LOR[7], W[2 * o + 9], sa);
            }
            accA[o] = sa;
        }
        const int t0 = 4 * m;
        if (SCALE_A) {
            dstA[t0 + 0] = accA[0]; dstA[t0 + 1] = accA[1];
            dstA[t0 + 2] = accA[2]; dstA[t0 + 3] = accA[3];
        } else {
            float4 qa; qa.x = accA[0]; qa.y = accA[1]; qa.z = accA[2]; qa.w = accA[3];
            *(reinterpret_cast<float4*>(dstA) + m) = qa;
        }
        outD[t0 + 0] = accD[0]; outD[t0 + 1] = accD[1];
        outD[t0 + 2] = accD[2]; outD[t0 + 3] = accD[3];
    }

    // Specials: t in {0..3} and {4*Mmax+4 .. N-1} (<= 10 of them)
    const int NS = N - 4 * Mmax;
    if (tid < NS) {
        const int t = (tid < 4) ? tid : (4 * Mmax + tid);
        float slo, shi;
        dwt_one_clamped(src, L, t, slo, shi);
        dstA[t] = SCALE_A ? fmaf(wa, slo, ba) : slo;
        outD[t] = fmaf(wd, shi, bd);
    }
}

__global__ __launch_bounds__(NT) void lwt_kernel(const float* __restrict__ x,
                                                 const float* __restrict__ w,
                                                 const float* __restrict__ bias,
                                                 float* __restrict__ out) {
    __shared__ __align__(16) float P[N1];  // cA1, later reused for cA3
    __shared__ __align__(16) float Q[N2];  // cA2
    const int row = blockIdx.x;
    const int tid = threadIdx.x;
    const float* __restrict__ xr = x + (size_t)row * LVL1;

    const float w0 = w[0], w1 = w[1], w2 = w[2], w3 = w[3], w4 = w[4];
    const float b0 = bias[0], b1 = bias[1], b2 = bias[2], b3 = bias[3], b4 = bias[4];

    float* outCD1 = out + OFF_CD1 + (size_t)row * N1;
    float* outCD2 = out + OFF_CD2 + (size_t)row * N2;
    float* outCD3 = out + OFF_CD3 + (size_t)row * N3;
    float* outCD4 = out + OFF_CD4 + (size_t)row * N4;
    float* outCA4 = out + OFF_CA4 + (size_t)row * N4;

    // ---- Level 1 from GLOBAL: t0 = 4m, m = 1..511, window floats [8m-8, 8m+8). ----
    {
        constexpr float LOR[8] = {L7f, L6f, L5f, L4f, L3f, L2f, L1f, L0};
        constexpr float HIR[8] = {L0, -L1f, L2f, -L3f, L4f, -L5f, L6f, -L7f};
        const float h0 = w4 * HIR[0], h1 = w4 * HIR[1], h2 = w4 * HIR[2], h3 = w4 * HIR[3],
                    h4 = w4 * HIR[4], h5 = w4 * HIR[5], h6 = w4 * HIR[6], h7 = w4 * HIR[7];
        for (int m = 1 + tid; m <= 511; m += NT) {
            const float4* p = reinterpret_cast<const float4*>(xr) + (2 * m - 2);
            const float4 v0 = p[0], v1 = p[1], v2 = p[2], v3 = p[3];
            const float W[16] = {v0.x, v0.y, v0.z, v0.w, v1.x, v1.y, v1.z, v1.w,
                                 v2.x, v2.y, v2.z, v2.w, v3.x, v3.y, v3.z, v3.w};
            float accA[4], accD[4];
#pragma unroll
            for (int o = 0; o < 4; ++o) {
                float sd = b4;
                sd = fmaf(h0, W[2 * o + 2], sd);
                sd = fmaf(h1, W[2 * o + 3], sd);
                sd = fmaf(h2, W[2 * o + 4], sd);
                sd = fmaf(h3, W[2 * o + 5], sd);
                sd = fmaf(h4, W[2 * o + 6], sd);
                sd = fmaf(h5, W[2 * o + 7], sd);
                sd = fmaf(h6, W[2 * o + 8], sd);
                sd = fmaf(h7, W[2 * o + 9], sd);
                accD[o] = sd;
                float sa = LOR[0] * W[2 * o + 2];
                sa = fmaf(LOR[1], W[2 * o + 3], sa);
                sa = fmaf(LOR[2], W[2 * o + 4], sa);
                sa = fmaf(LOR[3], W[2 * o + 5], sa);
                sa = fmaf(LOR[4], W[2 * o + 6], sa);
                sa = fmaf(LOR[5], W[2 * o + 7], sa);
                sa = fmaf(LOR[6], W[2 * o + 8], sa);
                sa = fmaf(LOR[7], W[2 * o + 9], sa);
                accA[o] = sa;
            }
            const int t0 = 4 * m;
            float4 qa; qa.x = accA[0]; qa.y = accA[1]; qa.z = accA[2]; qa.w = accA[3];
            *(reinterpret_cast<float4*>(P) + m) = qa;   // aligned b128, conflict-free
            outCD1[t0 + 0] = accD[0]; outCD1[t0 + 1] = accD[1];
            outCD1[t0 + 2] = accD[2]; outCD1[t0 + 3] = accD[3];
        }
        // Specials: t in {0,1,2,3} U {2048,2049,2050}  (m covers 4..2047)
        if (tid < 7) {
            const int t = (tid < 4) ? tid : (2044 + tid);
            float slo, shi;
            dwt_one_clamped(xr, LVL1, t, slo, shi);
            P[t] = slo;
            outCD1[t] = fmaf(w4, shi, b4);
        }
    }

    __syncthreads();
    dwt_level_blk<false>(P, N1, Q, 0.f, 0.f, outCD2, w3, b3);     // 2051 -> 1029
    __syncthreads();
    dwt_level_blk<false>(Q, N2, P, 0.f, 0.f, outCD3, w2, b2);     // 1029 -> 518
    __syncthreads();
    dwt_level_blk<true>(P, N3, outCA4, w0, b0, outCD4, w1, b1);   // 518 -> 262
}

extern "C" void kernel_launch(void* const* d_in, const int* in_sizes, int n_in,
                              void* d_out, int out_size, void* d_ws, size_t ws_size,
                              hipStream_t stream) {
    const float* x = (const float*)d_in[0];
    const float* wp = (const float*)d_in[1];
    const float* bp = (const float*)d_in[2];
    float* out = (float*)d_out;
    lwt_kernel<<<dim3(B_ROWS), dim3(NT), 0, stream>>>(x, wp, bp, out);
}